// Round 1
// 336.753 us; speedup vs baseline: 1.1366x; 1.1366x over previous
//
#include <hip/hip_runtime.h>

// GAT layer: B=2, N=50000, D=64, H=4, d=16, O=64, E=800000
#define N_NODES 50000
#define N_EDGES 800000
#define NEG_SLOPE 0.1f

static __device__ __forceinline__ float lrelu(float z) {
    return (z > 0.f) ? z : NEG_SLOPE * z;
}

// ws layout (floats):
//  feat    [N][B][H][d] : 6,400,000
//  el      [N][B*H]     :   400,000
//  er      [N][B*H]     :   400,000
//  denom   [N][B*H]     :   400,000
//  rst     [N][B][H][d] : 6,400,000
//  offsets [N] i32, cursor [N] i32, deg [N] i32, gctr [16] i32
//  srcw    [E] int2  (dst-grouped (src, w) pairs; group order arbitrary)

// ---- Kernel 1: feat = x @ W_fc.T (+ fused el/er), 4x4 register tile --------
// grid 1563: 64 rows/block. Thread (tc=t&15, tr=t>>4) computes rows tr*4+rr,
// cols jj*16+tc (jj = head index). Per k4: 8 ds_read_b128 for 64 FMA-instrs
// (vs 5 per 16 before) -- LDS-pipe pressure cut 2.5x. el/er via LDS-staged
// tile + in-register 16-dot (no 128-shuffle reduction).
__global__ __launch_bounds__(256, 4) void k_fc(const float* __restrict__ x,
                                               const float* __restrict__ Wfc,
                                               const float* __restrict__ al,
                                               const float* __restrict__ ar,
                                               float* __restrict__ feat,
                                               float* __restrict__ el,
                                               float* __restrict__ er) {
    __shared__ float Ws[64 * 68];   // pad 68: 16B-aligned rows, 2-way max
    __shared__ float xs[64 * 68];   // also reused to stage the output tile
    const int t = threadIdx.x;
    const int m0 = blockIdx.x * 64;

    // fills: coalesced float4, 4 + 4 per thread
#pragma unroll
    for (int i = 0; i < 4; ++i) {
        const int q = i * 256 + t;          // 1024 float4 = 64x64 W
        const int row = q >> 4, c = q & 15;
        *(float4*)&Ws[row * 68 + c * 4] = ((const float4*)Wfc)[q];
    }
#pragma unroll
    for (int i = 0; i < 4; ++i) {
        const int q = i * 256 + t;          // 64 rows of x
        const int row = q >> 4, c = q & 15;
        const int m = m0 + row;             // m = b*N + n
        float4 v = make_float4(0.f, 0.f, 0.f, 0.f);
        if (m < 2 * N_NODES) v = ((const float4*)x)[m * 16 + c];
        *(float4*)&xs[row * 68 + c * 4] = v;
    }
    __syncthreads();

    const int tc = t & 15, tr = t >> 4;
    float acc[4][4];                        // [rr][jj]
#pragma unroll
    for (int rr = 0; rr < 4; ++rr)
#pragma unroll
        for (int jj = 0; jj < 4; ++jj) acc[rr][jj] = 0.f;

#pragma unroll
    for (int k4 = 0; k4 < 16; ++k4) {
        float4 xv[4], wv[4];
#pragma unroll
        for (int rr = 0; rr < 4; ++rr)
            xv[rr] = *(const float4*)&xs[(tr * 4 + rr) * 68 + k4 * 4];   // 4-addr broadcast
#pragma unroll
        for (int jj = 0; jj < 4; ++jj)
            wv[jj] = *(const float4*)&Ws[(jj * 16 + tc) * 68 + k4 * 4];  // 2-way max
#pragma unroll
        for (int rr = 0; rr < 4; ++rr)
#pragma unroll
            for (int jj = 0; jj < 4; ++jj) {
                acc[rr][jj] = fmaf(xv[rr].x, wv[jj].x, acc[rr][jj]);
                acc[rr][jj] = fmaf(xv[rr].y, wv[jj].y, acc[rr][jj]);
                acc[rr][jj] = fmaf(xv[rr].z, wv[jj].z, acc[rr][jj]);
                acc[rr][jj] = fmaf(xv[rr].w, wv[jj].w, acc[rr][jj]);
            }
    }

    // stage output tile into xs (x no longer needed)
    __syncthreads();
#pragma unroll
    for (int rr = 0; rr < 4; ++rr)
#pragma unroll
        for (int jj = 0; jj < 4; ++jj)
            xs[(tr * 4 + rr) * 68 + jj * 16 + tc] = acc[rr][jj];
    __syncthreads();

    // feat stores: coalesced float4 from staged tile
#pragma unroll
    for (int i = 0; i < 4; ++i) {
        const int q = i * 256 + t;
        const int row = q >> 4, c = q & 15;
        const int m = m0 + row;
        if (m < 2 * N_NODES) {
            const float4 v = *(const float4*)&xs[row * 68 + c * 4];
            const int b = (m >= N_NODES) ? 1 : 0;
            const int n = m - b * N_NODES;
            ((float4*)feat)[n * 32 + b * 16 + c] = v;
        }
    }

    // el/er: thread owns one (row, head); 16-wide dot fully in registers
    {
        const int row2 = t >> 2, h = t & 3;
        const float* fr = &xs[row2 * 68 + h * 16];
        const float4 f0 = *(const float4*)&fr[0];
        const float4 f1 = *(const float4*)&fr[4];
        const float4 f2 = *(const float4*)&fr[8];
        const float4 f3 = *(const float4*)&fr[12];
        const float4* al4 = (const float4*)al;
        const float4* ar4 = (const float4*)ar;
        const float4 a0 = al4[h * 4 + 0], a1 = al4[h * 4 + 1];
        const float4 a2 = al4[h * 4 + 2], a3 = al4[h * 4 + 3];
        const float4 b0 = ar4[h * 4 + 0], b1 = ar4[h * 4 + 1];
        const float4 b2 = ar4[h * 4 + 2], b3 = ar4[h * 4 + 3];
        float sl = f0.x * a0.x;
        sl = fmaf(f0.y, a0.y, sl); sl = fmaf(f0.z, a0.z, sl); sl = fmaf(f0.w, a0.w, sl);
        sl = fmaf(f1.x, a1.x, sl); sl = fmaf(f1.y, a1.y, sl);
        sl = fmaf(f1.z, a1.z, sl); sl = fmaf(f1.w, a1.w, sl);
        sl = fmaf(f2.x, a2.x, sl); sl = fmaf(f2.y, a2.y, sl);
        sl = fmaf(f2.z, a2.z, sl); sl = fmaf(f2.w, a2.w, sl);
        sl = fmaf(f3.x, a3.x, sl); sl = fmaf(f3.y, a3.y, sl);
        sl = fmaf(f3.z, a3.z, sl); sl = fmaf(f3.w, a3.w, sl);
        float sr = f0.x * b0.x;
        sr = fmaf(f0.y, b0.y, sr); sr = fmaf(f0.z, b0.z, sr); sr = fmaf(f0.w, b0.w, sr);
        sr = fmaf(f1.x, b1.x, sr); sr = fmaf(f1.y, b1.y, sr);
        sr = fmaf(f1.z, b1.z, sr); sr = fmaf(f1.w, b1.w, sr);
        sr = fmaf(f2.x, b2.x, sr); sr = fmaf(f2.y, b2.y, sr);
        sr = fmaf(f2.z, b2.z, sr); sr = fmaf(f2.w, b2.w, sr);
        sr = fmaf(f3.x, b3.x, sr); sr = fmaf(f3.y, b3.y, sr);
        sr = fmaf(f3.w, b3.w, sr); sr = fmaf(f3.z, b3.z, sr);
        const int m = m0 + row2;
        if (m < 2 * N_NODES) {
            const int b = (m >= N_NODES) ? 1 : 0;
            const int n = m - b * N_NODES;
            el[n * 8 + b * 4 + h] = sl;
            er[n * 8 + b * 4 + h] = sr;
        }
    }
}

// ---- CSR build --------------------------------------------------------------
__global__ __launch_bounds__(256) void k_hist(const int* __restrict__ dst,
                                              int* __restrict__ deg) {
    const int e = blockIdx.x * 256 + threadIdx.x;   // grid exact 800000/256
    atomicAdd(&deg[dst[e]], 1);
}

// wave-aggregated base allocation: no global scan, group order arbitrary
__global__ __launch_bounds__(256) void k_alloc(const int* __restrict__ deg,
                                               int* __restrict__ offsets,
                                               int* __restrict__ cursor,
                                               int* __restrict__ gctr) {
    const int i = blockIdx.x * 256 + threadIdx.x;   // grid 196 covers 50176
    const int lane = threadIdx.x & 63;
    const int d = (i < N_NODES) ? deg[i] : 0;
    int incl = d;
#pragma unroll
    for (int off = 1; off < 64; off <<= 1) {
        int v = __shfl_up(incl, off, 64);
        if (lane >= off) incl += v;
    }
    const int wtot = __shfl(incl, 63, 64);
    int wbase = 0;
    if (lane == 63) wbase = atomicAdd(gctr, wtot);
    wbase = __shfl(wbase, 63, 64);
    if (i < N_NODES) {
        const int beg = wbase + incl - d;
        offsets[i] = beg;
        cursor[i] = beg;
    }
}

__global__ __launch_bounds__(256) void k_scatter(const int* __restrict__ src,
                                                 const int* __restrict__ dst,
                                                 const float* __restrict__ w,
                                                 int* __restrict__ cursor,
                                                 int2* __restrict__ srcw) {
    const int e = blockIdx.x * 256 + threadIdx.x;
    const int pos = atomicAdd(&cursor[dst[e]], 1);
    srcw[pos] = make_int2(src[e], __float_as_int(w[e]));
}

// ---- Kernel 2: per-dst gather — softmax numerator + weighted sum ------------
// 32 threads/node, 8 nodes per 256-block; thread handles float4 (sub in [0,32))
__global__ __launch_bounds__(256) void k_gather(const int2* __restrict__ srcw,
                                                const int* __restrict__ offsets,
                                                const int* __restrict__ deg,
                                                const float* __restrict__ el,
                                                const float* __restrict__ er,
                                                const float* __restrict__ feat,
                                                float* __restrict__ denom,
                                                float* __restrict__ rst) {
    const int t = threadIdx.x;
    const int n = blockIdx.x * 8 + (t >> 5);   // grid exact 50000/8
    const int sub = t & 31, c = sub >> 2;
    const int beg = offsets[n], len = deg[n];
    const float ern = er[n * 8 + c];
    const float4* feat4 = (const float4*)feat;
    float4 acc = make_float4(0.f, 0.f, 0.f, 0.f);
    float den = 0.f;
    int k = 0;
    for (; k + 2 <= len; k += 2) {             // 2-way unroll: 2 load chains
        const int2 s0 = srcw[beg + k];
        const int2 s1 = srcw[beg + k + 1];
        const float e0 = el[s0.x * 8 + c];
        const float e1 = el[s1.x * 8 + c];
        const float4 f0 = feat4[s0.x * 32 + sub];
        const float4 f1 = feat4[s1.x * 32 + sub];
        const float x0 = __expf(__int_as_float(s0.y) * lrelu(e0 + ern));
        const float x1 = __expf(__int_as_float(s1.y) * lrelu(e1 + ern));
        den += x0 + x1;
        acc.x = fmaf(x0, f0.x, acc.x); acc.y = fmaf(x0, f0.y, acc.y);
        acc.z = fmaf(x0, f0.z, acc.z); acc.w = fmaf(x0, f0.w, acc.w);
        acc.x = fmaf(x1, f1.x, acc.x); acc.y = fmaf(x1, f1.y, acc.y);
        acc.z = fmaf(x1, f1.z, acc.z); acc.w = fmaf(x1, f1.w, acc.w);
    }
    if (k < len) {
        const int2 s0 = srcw[beg + k];
        const float e0 = el[s0.x * 8 + c];
        const float4 f0 = feat4[s0.x * 32 + sub];
        const float x0 = __expf(__int_as_float(s0.y) * lrelu(e0 + ern));
        den += x0;
        acc.x = fmaf(x0, f0.x, acc.x); acc.y = fmaf(x0, f0.y, acc.y);
        acc.z = fmaf(x0, f0.z, acc.z); acc.w = fmaf(x0, f0.w, acc.w);
    }
    ((float4*)rst)[n * 32 + sub] = acc;
    if ((sub & 3) == 0) denom[n * 8 + c] = den;
}

// ---- Kernel 3: out = (rst/denom) @ W_out.T + b_out, layout [B,N,H,O] --------
// grid 6250: 64 groups/block; W_out row in registers, rs via LDS broadcast b128
__global__ __launch_bounds__(256) void k_out(const float* __restrict__ rst,
                                             const float* __restrict__ denom,
                                             const float* __restrict__ Wout,
                                             const float* __restrict__ bout,
                                             float* __restrict__ out) {
    __shared__ float rs[1024];
    __shared__ float dn[64];
    const int t = threadIdx.x;
    const int o = t & 63, r = t >> 6;
#pragma unroll
    for (int i = 0; i < 4; ++i)
        rs[i * 256 + t] = rst[blockIdx.x * 1024 + i * 256 + t];
    if (t < 64) dn[t] = denom[blockIdx.x * 64 + t];
    __syncthreads();

    const float4* Wo4 = (const float4*)Wout;
    const float4 wa = Wo4[o * 4 + 0], wb = Wo4[o * 4 + 1];
    const float4 wc = Wo4[o * 4 + 2], wd = Wo4[o * 4 + 3];
    const float bo = bout[o];
#pragma unroll
    for (int i = 0; i < 16; ++i) {
        const int gl = i * 4 + r;              // local g, 0..63
        const float dv = dn[gl];
        const float dinv = (dv > 0.f) ? 1.f / dv : 0.f;
        const float4* r4 = (const float4*)&rs[gl * 16];
        const float4 ra = r4[0], rb = r4[1], rc = r4[2], rd = r4[3];
        float acc = ra.x * wa.x;
        acc = fmaf(ra.y, wa.y, acc); acc = fmaf(ra.z, wa.z, acc); acc = fmaf(ra.w, wa.w, acc);
        acc = fmaf(rb.x, wb.x, acc); acc = fmaf(rb.y, wb.y, acc);
        acc = fmaf(rb.z, wb.z, acc); acc = fmaf(rb.w, wb.w, acc);
        acc = fmaf(rc.x, wc.x, acc); acc = fmaf(rc.y, wc.y, acc);
        acc = fmaf(rc.z, wc.z, acc); acc = fmaf(rc.w, wc.w, acc);
        acc = fmaf(rd.x, wd.x, acc); acc = fmaf(rd.y, wd.y, acc);
        acc = fmaf(rd.z, wd.z, acc); acc = fmaf(rd.w, wd.w, acc);
        acc = fmaf(acc, dinv, bo);
        const int g = blockIdx.x * 64 + gl;    // g = n*8 + b*4 + h
        const int n = g >> 3, b = (g >> 2) & 1, h = g & 3;
        out[b * (N_NODES * 256) + n * 256 + h * 64 + o] = acc;
    }
}

extern "C" void kernel_launch(void* const* d_in, const int* in_sizes, int n_in,
                              void* d_out, int out_size, void* d_ws, size_t ws_size,
                              hipStream_t stream) {
    // setup_inputs order: vt, x, w, src, dst, W_fc, attn_l, attn_r, W_out, b_out
    const float* x    = (const float*)d_in[1];
    const float* w    = (const float*)d_in[2];
    const int*   src  = (const int*)  d_in[3];
    const int*   dst  = (const int*)  d_in[4];
    const float* Wfc  = (const float*)d_in[5];
    const float* al   = (const float*)d_in[6];
    const float* ar   = (const float*)d_in[7];
    const float* Wout = (const float*)d_in[8];
    const float* bout = (const float*)d_in[9];
    float* out = (float*)d_out;

    float* ws    = (float*)d_ws;
    float* feat  = ws;                  // 6,400,000
    float* el    = feat + 6400000;      //   400,000
    float* er    = el + 400000;         //   400,000
    float* denom = er + 400000;         //   400,000
    float* rst   = denom + 400000;      // 6,400,000
    int*   offsets = (int*)(rst + 6400000);   // 50,000
    int*   cursor  = offsets + 50000;         // 50,000
    int*   deg     = cursor + 50000;          // 50,000
    int*   gctr    = deg + 50000;             // 16 (pad)
    int2*  srcw    = (int2*)(gctr + 16);      // 800,000 int2

    hipMemsetAsync(deg, 0, (50000 + 16) * sizeof(int), stream);  // deg + gctr

    k_fc<<<1563, 256, 0, stream>>>(x, Wfc, al, ar, feat, el, er);
    k_hist<<<N_EDGES / 256, 256, 0, stream>>>(dst, deg);
    k_alloc<<<196, 256, 0, stream>>>(deg, offsets, cursor, gctr);
    k_scatter<<<N_EDGES / 256, 256, 0, stream>>>(src, dst, w, cursor, srcw);
    k_gather<<<N_NODES / 8, 256, 0, stream>>>(srcw, offsets, deg, el, er, feat, denom, rst);
    k_out<<<6250, 256, 0, stream>>>(rst, denom, Wout, bout, out);
}

// Round 3
// 304.406 us; speedup vs baseline: 1.2574x; 1.1063x over previous
//
#include <hip/hip_runtime.h>
#include <hip/hip_fp16.h>

// GAT layer: B=2, N=50000, D=64, H=4, d=16, O=64, E=800000
#define N_NODES 50000
#define N_EDGES 800000
#define NEG_SLOPE 0.1f

static __device__ __forceinline__ float lrelu(float z) {
    return (z > 0.f) ? z : NEG_SLOPE * z;
}

// ws layout (floats):
//  feat_h  [N][B][H][d] half : 3,200,000 floats of space (6.4M halves)
//  el      [N][B*H]          :   400,000
//  er      [N][B*H]          :   400,000
//  denom   [N][B*H]          :   400,000
//  rst_h   [N][B][H][d] half : 3,200,000 floats of space (6.4M halves)
//  offsets [N] i32, cursor [N] i32, deg [N] i32, gctr [16] i32
//  srcw    [E] int2  (dst-grouped (src, w) pairs; group order arbitrary)

// ---- Kernel 1: feat = x @ W_fc.T (+ fused el/er), 4x4 register tile --------
// grid 1563: 64 rows/block. feat written as fp16 (gather reads it as half8;
// comparison quantum is ~bf16 ulp so fp16 storage error is invisible).
__global__ __launch_bounds__(256, 4) void k_fc(const float* __restrict__ x,
                                               const float* __restrict__ Wfc,
                                               const float* __restrict__ al,
                                               const float* __restrict__ ar,
                                               __half* __restrict__ feat_h,
                                               float* __restrict__ el,
                                               float* __restrict__ er) {
    __shared__ float Ws[64 * 68];   // pad 68: 16B-aligned rows, 2-way max
    __shared__ float xs[64 * 68];   // also reused to stage the output tile
    const int t = threadIdx.x;
    const int m0 = blockIdx.x * 64;

#pragma unroll
    for (int i = 0; i < 4; ++i) {
        const int q = i * 256 + t;          // 1024 float4 = 64x64 W
        const int row = q >> 4, c = q & 15;
        *(float4*)&Ws[row * 68 + c * 4] = ((const float4*)Wfc)[q];
    }
#pragma unroll
    for (int i = 0; i < 4; ++i) {
        const int q = i * 256 + t;          // 64 rows of x
        const int row = q >> 4, c = q & 15;
        const int m = m0 + row;             // m = b*N + n
        float4 v = make_float4(0.f, 0.f, 0.f, 0.f);
        if (m < 2 * N_NODES) v = ((const float4*)x)[m * 16 + c];
        *(float4*)&xs[row * 68 + c * 4] = v;
    }
    __syncthreads();

    const int tc = t & 15, tr = t >> 4;
    float acc[4][4];                        // [rr][jj]
#pragma unroll
    for (int rr = 0; rr < 4; ++rr)
#pragma unroll
        for (int jj = 0; jj < 4; ++jj) acc[rr][jj] = 0.f;

#pragma unroll
    for (int k4 = 0; k4 < 16; ++k4) {
        float4 xv[4], wv[4];
#pragma unroll
        for (int rr = 0; rr < 4; ++rr)
            xv[rr] = *(const float4*)&xs[(tr * 4 + rr) * 68 + k4 * 4];
#pragma unroll
        for (int jj = 0; jj < 4; ++jj)
            wv[jj] = *(const float4*)&Ws[(jj * 16 + tc) * 68 + k4 * 4];
#pragma unroll
        for (int rr = 0; rr < 4; ++rr)
#pragma unroll
            for (int jj = 0; jj < 4; ++jj) {
                acc[rr][jj] = fmaf(xv[rr].x, wv[jj].x, acc[rr][jj]);
                acc[rr][jj] = fmaf(xv[rr].y, wv[jj].y, acc[rr][jj]);
                acc[rr][jj] = fmaf(xv[rr].z, wv[jj].z, acc[rr][jj]);
                acc[rr][jj] = fmaf(xv[rr].w, wv[jj].w, acc[rr][jj]);
            }
    }

    // stage output tile into xs (x no longer needed)
    __syncthreads();
#pragma unroll
    for (int rr = 0; rr < 4; ++rr)
#pragma unroll
        for (int jj = 0; jj < 4; ++jj)
            xs[(tr * 4 + rr) * 68 + jj * 16 + tc] = acc[rr][jj];
    __syncthreads();

    // feat stores: fp16 half8 (16B) per thread-iter, 2 iters cover the tile
#pragma unroll
    for (int i = 0; i < 2; ++i) {
        const int q = i * 256 + t;          // 512 half8-groups
        const int row = q >> 3, c8 = q & 7;
        const int m = m0 + row;
        if (m < 2 * N_NODES) {
            const float4 fA = *(const float4*)&xs[row * 68 + c8 * 8];
            const float4 fB = *(const float4*)&xs[row * 68 + c8 * 8 + 4];
            const int b = (m >= N_NODES) ? 1 : 0;
            const int n = m - b * N_NODES;
            __half2 h0 = __floats2half2_rn(fA.x, fA.y);
            __half2 h1 = __floats2half2_rn(fA.z, fA.w);
            __half2 h2 = __floats2half2_rn(fB.x, fB.y);
            __half2 h3 = __floats2half2_rn(fB.z, fB.w);
            uint4 pack;
            pack.x = *(unsigned int*)&h0;
            pack.y = *(unsigned int*)&h1;
            pack.z = *(unsigned int*)&h2;
            pack.w = *(unsigned int*)&h3;
            ((uint4*)feat_h)[n * 16 + b * 8 + c8] = pack;
        }
    }

    // el/er: thread owns one (row, head); 16-wide dot fully in registers
    {
        const int row2 = t >> 2, h = t & 3;
        const float* fr = &xs[row2 * 68 + h * 16];
        const float4 f0 = *(const float4*)&fr[0];
        const float4 f1 = *(const float4*)&fr[4];
        const float4 f2 = *(const float4*)&fr[8];
        const float4 f3 = *(const float4*)&fr[12];
        const float4* al4 = (const float4*)al;
        const float4* ar4 = (const float4*)ar;
        const float4 a0 = al4[h * 4 + 0], a1 = al4[h * 4 + 1];
        const float4 a2 = al4[h * 4 + 2], a3 = al4[h * 4 + 3];
        const float4 b0 = ar4[h * 4 + 0], b1 = ar4[h * 4 + 1];
        const float4 b2 = ar4[h * 4 + 2], b3 = ar4[h * 4 + 3];
        float sl = f0.x * a0.x;
        sl = fmaf(f0.y, a0.y, sl); sl = fmaf(f0.z, a0.z, sl); sl = fmaf(f0.w, a0.w, sl);
        sl = fmaf(f1.x, a1.x, sl); sl = fmaf(f1.y, a1.y, sl);
        sl = fmaf(f1.z, a1.z, sl); sl = fmaf(f1.w, a1.w, sl);
        sl = fmaf(f2.x, a2.x, sl); sl = fmaf(f2.y, a2.y, sl);
        sl = fmaf(f2.z, a2.z, sl); sl = fmaf(f2.w, a2.w, sl);
        sl = fmaf(f3.x, a3.x, sl); sl = fmaf(f3.y, a3.y, sl);
        sl = fmaf(f3.z, a3.z, sl); sl = fmaf(f3.w, a3.w, sl);
        float sr = f0.x * b0.x;
        sr = fmaf(f0.y, b0.y, sr); sr = fmaf(f0.z, b0.z, sr); sr = fmaf(f0.w, b0.w, sr);
        sr = fmaf(f1.x, b1.x, sr); sr = fmaf(f1.y, b1.y, sr);
        sr = fmaf(f1.z, b1.z, sr); sr = fmaf(f1.w, b1.w, sr);
        sr = fmaf(f2.x, b2.x, sr); sr = fmaf(f2.y, b2.y, sr);
        sr = fmaf(f2.z, b2.z, sr); sr = fmaf(f2.w, b2.w, sr);
        sr = fmaf(f3.x, b3.x, sr); sr = fmaf(f3.y, b3.y, sr);
        sr = fmaf(f3.z, b3.z, sr); sr = fmaf(f3.w, b3.w, sr);
        const int m = m0 + row2;
        if (m < 2 * N_NODES) {
            const int b = (m >= N_NODES) ? 1 : 0;
            const int n = m - b * N_NODES;
            el[n * 8 + b * 4 + h] = sl;
            er[n * 8 + b * 4 + h] = sr;
        }
    }
}

// ---- CSR build --------------------------------------------------------------
__global__ __launch_bounds__(256) void k_hist(const int* __restrict__ dst,
                                              int* __restrict__ deg) {
    const int e = blockIdx.x * 256 + threadIdx.x;   // grid exact 800000/256
    atomicAdd(&deg[dst[e]], 1);
}

__global__ __launch_bounds__(256) void k_alloc(const int* __restrict__ deg,
                                               int* __restrict__ offsets,
                                               int* __restrict__ cursor,
                                               int* __restrict__ gctr) {
    const int i = blockIdx.x * 256 + threadIdx.x;   // grid 196 covers 50176
    const int lane = threadIdx.x & 63;
    const int d = (i < N_NODES) ? deg[i] : 0;
    int incl = d;
#pragma unroll
    for (int off = 1; off < 64; off <<= 1) {
        int v = __shfl_up(incl, off, 64);
        if (lane >= off) incl += v;
    }
    const int wtot = __shfl(incl, 63, 64);
    int wbase = 0;
    if (lane == 63) wbase = atomicAdd(gctr, wtot);
    wbase = __shfl(wbase, 63, 64);
    if (i < N_NODES) {
        const int beg = wbase + incl - d;
        offsets[i] = beg;
        cursor[i] = beg;
    }
}

__global__ __launch_bounds__(256) void k_scatter(const int* __restrict__ src,
                                                 const int* __restrict__ dst,
                                                 const float* __restrict__ w,
                                                 int* __restrict__ cursor,
                                                 int2* __restrict__ srcw) {
    const int e = blockIdx.x * 256 + threadIdx.x;
    const int pos = atomicAdd(&cursor[dst[e]], 1);
    srcw[pos] = make_int2(src[e], __float_as_int(w[e]));
}

// ---- Kernel 2: per-dst gather — softmax numerator + weighted sum ------------
// 16 threads/node, 16 nodes per 256-block. Lane sub owns 8 consecutive halves
// (one uint4) of the 128-half feat row -> 256 B/edge gather (was 512 B fp32).
// 4-way unroll: 4 independent 16B gather chains per lane for MLP.
static __device__ __forceinline__ void acc8(float* acc, const uint4& g, float xx) {
    const __half2* hp = (const __half2*)&g;
    float2 p;
    p = __half22float2(hp[0]); acc[0] = fmaf(xx, p.x, acc[0]); acc[1] = fmaf(xx, p.y, acc[1]);
    p = __half22float2(hp[1]); acc[2] = fmaf(xx, p.x, acc[2]); acc[3] = fmaf(xx, p.y, acc[3]);
    p = __half22float2(hp[2]); acc[4] = fmaf(xx, p.x, acc[4]); acc[5] = fmaf(xx, p.y, acc[5]);
    p = __half22float2(hp[3]); acc[6] = fmaf(xx, p.x, acc[6]); acc[7] = fmaf(xx, p.y, acc[7]);
}

__global__ __launch_bounds__(256) void k_gather(const int2* __restrict__ srcw,
                                                const int* __restrict__ offsets,
                                                const int* __restrict__ deg,
                                                const float* __restrict__ el,
                                                const float* __restrict__ er,
                                                const __half* __restrict__ feat_h,
                                                float* __restrict__ denom,
                                                __half* __restrict__ rst_h) {
    const int t = threadIdx.x;
    const int n = blockIdx.x * 16 + (t >> 4);  // grid exact 50000/16
    const int sub = t & 15;
    // half index j = sub*8 + [0,8): b = sub>>3, h = (sub>>1)&3
    const int c = ((sub >> 3) << 2) | ((sub >> 1) & 3);
    const int beg = offsets[n], len = deg[n];
    const float ern = er[n * 8 + c];
    const uint4* f4 = (const uint4*)feat_h;
    float acc[8] = {0.f, 0.f, 0.f, 0.f, 0.f, 0.f, 0.f, 0.f};
    float den = 0.f;
    int k = 0;
    for (; k + 4 <= len; k += 4) {
        const int2 s0 = srcw[beg + k];
        const int2 s1 = srcw[beg + k + 1];
        const int2 s2 = srcw[beg + k + 2];
        const int2 s3 = srcw[beg + k + 3];
        const float e0 = el[s0.x * 8 + c];
        const float e1 = el[s1.x * 8 + c];
        const float e2 = el[s2.x * 8 + c];
        const float e3 = el[s3.x * 8 + c];
        const uint4 g0 = f4[s0.x * 16 + sub];
        const uint4 g1 = f4[s1.x * 16 + sub];
        const uint4 g2 = f4[s2.x * 16 + sub];
        const uint4 g3 = f4[s3.x * 16 + sub];
        const float x0 = __expf(__int_as_float(s0.y) * lrelu(e0 + ern));
        const float x1 = __expf(__int_as_float(s1.y) * lrelu(e1 + ern));
        const float x2 = __expf(__int_as_float(s2.y) * lrelu(e2 + ern));
        const float x3 = __expf(__int_as_float(s3.y) * lrelu(e3 + ern));
        den += (x0 + x1) + (x2 + x3);
        acc8(acc, g0, x0); acc8(acc, g1, x1);
        acc8(acc, g2, x2); acc8(acc, g3, x3);
    }
    for (; k < len; ++k) {
        const int2 s0 = srcw[beg + k];
        const float e0 = el[s0.x * 8 + c];
        const uint4 g0 = f4[s0.x * 16 + sub];
        const float x0 = __expf(__int_as_float(s0.y) * lrelu(e0 + ern));
        den += x0;
        acc8(acc, g0, x0);
    }
    // store rst as fp16 half8 (coalesced 16B/lane)
    __half2 r0 = __floats2half2_rn(acc[0], acc[1]);
    __half2 r1 = __floats2half2_rn(acc[2], acc[3]);
    __half2 r2 = __floats2half2_rn(acc[4], acc[5]);
    __half2 r3 = __floats2half2_rn(acc[6], acc[7]);
    uint4 pack;
    pack.x = *(unsigned int*)&r0;
    pack.y = *(unsigned int*)&r1;
    pack.z = *(unsigned int*)&r2;
    pack.w = *(unsigned int*)&r3;
    ((uint4*)rst_h)[n * 16 + sub] = pack;
    if ((sub & 1) == 0) denom[n * 8 + c] = den;
}

// ---- Kernel 3: out = (rst/denom) @ W_out.T + b_out, layout [B,N,H,O] --------
// grid 6250: 64 groups/block; rst read as fp16, converted during LDS staging.
__global__ __launch_bounds__(256) void k_out(const __half* __restrict__ rst_h,
                                             const float* __restrict__ denom,
                                             const float* __restrict__ Wout,
                                             const float* __restrict__ bout,
                                             float* __restrict__ out) {
    __shared__ float rs[1024];
    __shared__ float dn[64];
    const int t = threadIdx.x;
    const int o = t & 63, r = t >> 6;
    {
        const uint2 hv = ((const uint2*)rst_h)[blockIdx.x * 256 + t];  // 4 halves
        const __half2* hp = (const __half2*)&hv;
        const float2 q0 = __half22float2(hp[0]);
        const float2 q1 = __half22float2(hp[1]);
        *(float4*)&rs[4 * t] = make_float4(q0.x, q0.y, q1.x, q1.y);
    }
    if (t < 64) dn[t] = denom[blockIdx.x * 64 + t];
    __syncthreads();

    const float4* Wo4 = (const float4*)Wout;
    const float4 wa = Wo4[o * 4 + 0], wb = Wo4[o * 4 + 1];
    const float4 wc = Wo4[o * 4 + 2], wd = Wo4[o * 4 + 3];
    const float bo = bout[o];
#pragma unroll
    for (int i = 0; i < 16; ++i) {
        const int gl = i * 4 + r;              // local g, 0..63
        const float dv = dn[gl];
        const float dinv = (dv > 0.f) ? 1.f / dv : 0.f;
        const float4* r4 = (const float4*)&rs[gl * 16];
        const float4 ra = r4[0], rb = r4[1], rc = r4[2], rd = r4[3];
        float acc = ra.x * wa.x;
        acc = fmaf(ra.y, wa.y, acc); acc = fmaf(ra.z, wa.z, acc); acc = fmaf(ra.w, wa.w, acc);
        acc = fmaf(rb.x, wb.x, acc); acc = fmaf(rb.y, wb.y, acc);
        acc = fmaf(rb.z, wb.z, acc); acc = fmaf(rb.w, wb.w, acc);
        acc = fmaf(rc.x, wc.x, acc); acc = fmaf(rc.y, wc.y, acc);
        acc = fmaf(rc.z, wc.z, acc); acc = fmaf(rc.w, wc.w, acc);
        acc = fmaf(rd.x, wd.x, acc); acc = fmaf(rd.y, wd.y, acc);
        acc = fmaf(rd.z, wd.z, acc); acc = fmaf(rd.w, wd.w, acc);
        acc = fmaf(acc, dinv, bo);
        const int g = blockIdx.x * 64 + gl;    // g = n*8 + b*4 + h
        const int n = g >> 3, b = (g >> 2) & 1, h = g & 3;
        out[b * (N_NODES * 256) + n * 256 + h * 64 + o] = acc;
    }
}

extern "C" void kernel_launch(void* const* d_in, const int* in_sizes, int n_in,
                              void* d_out, int out_size, void* d_ws, size_t ws_size,
                              hipStream_t stream) {
    // setup_inputs order: vt, x, w, src, dst, W_fc, attn_l, attn_r, W_out, b_out
    const float* x    = (const float*)d_in[1];
    const float* w    = (const float*)d_in[2];
    const int*   src  = (const int*)  d_in[3];
    const int*   dst  = (const int*)  d_in[4];
    const float* Wfc  = (const float*)d_in[5];
    const float* al   = (const float*)d_in[6];
    const float* ar   = (const float*)d_in[7];
    const float* Wout = (const float*)d_in[8];
    const float* bout = (const float*)d_in[9];
    float* out = (float*)d_out;

    float* ws    = (float*)d_ws;
    __half* feat_h = (__half*)ws;             // 6.4M halves = 3.2M floats
    float* el    = ws + 3200000;              //   400,000
    float* er    = el + 400000;               //   400,000
    float* denom = er + 400000;               //   400,000
    __half* rst_h = (__half*)(denom + 400000);// 6.4M halves = 3.2M floats
    int*   offsets = (int*)((float*)rst_h + 3200000);  // 50,000
    int*   cursor  = offsets + 50000;         // 50,000
    int*   deg     = cursor + 50000;          // 50,000
    int*   gctr    = deg + 50000;             // 16 (pad)
    int2*  srcw    = (int2*)(gctr + 16);      // 800,000 int2

    hipMemsetAsync(deg, 0, (50000 + 16) * sizeof(int), stream);  // deg + gctr

    k_fc<<<1563, 256, 0, stream>>>(x, Wfc, al, ar, feat_h, el, er);
    k_hist<<<N_EDGES / 256, 256, 0, stream>>>(dst, deg);
    k_alloc<<<196, 256, 0, stream>>>(deg, offsets, cursor, gctr);
    k_scatter<<<N_EDGES / 256, 256, 0, stream>>>(src, dst, w, cursor, srcw);
    k_gather<<<N_NODES / 16, 256, 0, stream>>>(srcw, offsets, deg, el, er, feat_h, denom, rst_h);
    k_out<<<6250, 256, 0, stream>>>(rst_h, denom, Wout, bout, out);
}